// Round 3
// baseline (145.515 us; speedup 1.0000x reference)
//
#include <hip/hip_runtime.h>
#include <stdint.h>

#define NFREQ 256
#define NB 16
#define NT 4096
#define LOUT 1048832          // (4096+1)*256
#define TROWS 65              // t = j0-1 .. j0+63
#define TROW 132              // u32 per T row: 128 payload + 4 pad (528 B, 16B-aligned)

typedef __bf16 bf16;
typedef __bf16 bf16x8 __attribute__((ext_vector_type(8)));
typedef float floatx4 __attribute__((ext_vector_type(4)));

__device__ inline uint32_t f_as_u(float x) { union { float f; uint32_t u; } v; v.f = x; return v.u; }
__device__ inline uint32_t bf16r(float x) {     // RNE bf16 bits in low 16
    uint32_t u = f_as_u(x);
    return (u + 0x7fffu + ((u >> 16) & 1u)) >> 16;
}

// kbF frag-major: kbF[k'/32][n][k'%32] = Kb[n][k'],
//   Kb[n][f'] = (f'<256 ? K[n+256][f'] : K[n][f'-256]) / 128  (bf16 RNE)
__global__ __launch_bounds__(256) void build_kb(const float* __restrict__ ker,
                                                bf16* __restrict__ kbF) {
    int idx = blockIdx.x * 256 + threadIdx.x;   // 131072 total
    int n = idx >> 9, f = idx & 511;
    float v = (f < 256) ? ker[(n + 256) * 256 + f] : ker[n * 256 + (f - 256)];
    uint32_t rr = bf16r(v * 0.0078125f);
    union { uint16_t u; bf16 b; } o; o.u = (uint16_t)rr;
    kbF[((size_t)(f >> 5) * 256 + n) * 32 + (f & 31)] = o.b;
}

// ---- staging macros (round-0 code, parameterized by buffer + tile j0) ----
#define STAGE_GROUP(TtB, J0, rb) { \
    float v_[16]; \
    _Pragma("unroll") \
    for (int i_ = 0; i_ < 16; ++i_) { \
        int r_ = (rb) * 16 + i_; int tc_ = r_ >> 5, fpi_ = r_ & 31; \
        int f_ = (fpw + fpi_) * 2 + lpar; \
        int t_ = (J0) - 1 + tc_ * 32 + lt; \
        v_[i_] = ((unsigned)t_ < (unsigned)NT) ? sb[(size_t)f_ * NT + t_] : 0.0f; } \
    _Pragma("unroll") \
    for (int i_ = 0; i_ < 16; i_ += 2) { \
        int r_ = (rb) * 16 + i_; int tc_ = r_ >> 5, fpi_ = r_ & 31; \
        int tl_ = tc_ * 32 + lt; \
        uint32_t h0_ = bf16r(v_[i_]);     uint32_t o0_ = (uint32_t)__shfl_xor((int)h0_, 1); \
        uint32_t h1_ = bf16r(v_[i_ + 1]); uint32_t o1_ = (uint32_t)__shfl_xor((int)h1_, 1); \
        if (lpar == 0) { \
            uint2 pk_; pk_.x = (h0_ & 0xffffu) | (o0_ << 16); pk_.y = (h1_ & 0xffffu) | (o1_ << 16); \
            *reinterpret_cast<uint2*>(&(TtB)[tl_ * TROW + fpw + fpi_]) = pk_; } } }

#define STAGE_ROW64(TtB, J0) { \
    int f_ = w * 64 + lane; int te_ = (J0) + 63; \
    float v_ = ((unsigned)te_ < (unsigned)NT) ? sb[(size_t)f_ * NT + te_] : 0.0f; \
    uint32_t h_ = bf16r(v_); uint32_t o_ = (uint32_t)__shfl_xor((int)h_, 1); \
    if (lpar == 0) (TtB)[64 * TROW + w * 32 + lt] = (h_ & 0xffffu) | (o_ << 16); }

#define LOADB(dst, kc) { \
    _Pragma("unroll") \
    for (int jn_ = 0; jn_ < 4; ++jn_) \
        dst[jn_] = *reinterpret_cast<const bf16x8*>( \
            kbw + (size_t)(kc) * 8192 + (jn_ * 16 + row16) * 32 + q * 8); }

#define LOADA(dst, Tb, kki, ks) { \
    _Pragma("unroll") \
    for (int i_ = 0; i_ < 4; ++i_) \
        dst[i_] = *reinterpret_cast<const bf16x8*>( \
            (Tb) + (size_t)(i_ * 16 + row16 + ((kki) >= 4 ? 1 : 0)) * 528 \
                 + ((kki) & 3) * 128 + (ks) * 64 + q * 16); }

#define DOMFMA(af_, bf_) { \
    _Pragma("unroll") \
    for (int i_ = 0; i_ < 4; ++i_) \
        _Pragma("unroll") \
        for (int jn_ = 0; jn_ < 4; ++jn_) \
            acc[i_][jn_] = __builtin_amdgcn_mfma_f32_16x16x32_bf16(af_[i_], bf_[jn_], acc[i_][jn_], 0, 0, 0); }

#define STORE_TILE(J0) { \
    _Pragma("unroll") \
    for (int i_ = 0; i_ < 4; ++i_) { \
        _Pragma("unroll") \
        for (int e_ = 0; e_ < 4; ++e_) { \
            int j_ = (J0) + i_ * 16 + q * 4 + e_; \
            if (j_ <= 4096) { \
                float* orow_ = out + (size_t)b * LOUT + (size_t)j_ * 256 + w * 64; \
                _Pragma("unroll") \
                for (int jn_ = 0; jn_ < 4; ++jn_) \
                    orow_[jn_ * 16 + row16] = acc[i_][jn_][e_]; } } } }

// out[b][j*256+n] = sum_{f'<512} Avirt[j][f'] * Kb[n][f'],
//   Avirt[j][f'] = spec[b][f'&255][j-1+(f'>=256)]   (0 outside t-range)
// Each block: TWO 64j x 256n tiles, double-buffered LDS. Tile1's staging is
// interleaved into tile0's MFMA chunk loop so the HBM fetch rides under
// compute; tile0's stores issue after the barrier and drain under tile1's
// compute. Breaks the stage->compute->store phase synchronization that held
// all previous variants at ~60us with every pipe <40%.
__global__ __launch_bounds__(256, 2) void imdct_gemm(const float* __restrict__ spec,
                                                     const bf16* __restrict__ kbF,
                                                     float* __restrict__ out) {
    __shared__ uint32_t Tt[2][TROWS * TROW];    // 2 x 34320 B = 68640 -> 2 blocks/CU

    const int b  = blockIdx.y;
    const int tid = threadIdx.x, lane = tid & 63, w = tid >> 6;
    const int j0t0 = blockIdx.x * 128;           // tile0 j-base (jt = 2*bx)
    const int j0t1 = j0t0 + 64;                  // tile1 j-base (jt = 2*bx+1)
    const bool has1 = (blockIdx.x < 32);         // bx=32 -> only boundary tile jt=64
    const float* sb = spec + (size_t)b * NFREQ * NT;

    const int lpar = lane & 1, lt = lane >> 1;
    const int fpw = w * 32;
    const int row16 = lane & 15, q = lane >> 4;
    const bf16* kbw = kbF + (size_t)w * 64 * 32;   // wave's n-slice base
    uint32_t* Tt0 = &Tt[0][0];
    uint32_t* Tt1 = &Tt[1][0];

    // ---- stage tile0 into buf0 ----
    STAGE_GROUP(Tt0, j0t0, 0);
    STAGE_GROUP(Tt0, j0t0, 1);
    STAGE_GROUP(Tt0, j0t0, 2);
    STAGE_GROUP(Tt0, j0t0, 3);
    STAGE_ROW64(Tt0, j0t0);
    __syncthreads();

    // ---- compute tile0, with tile1 staging embedded (writes to buf1) ----
    floatx4 acc[4][4] = {};
    {
        const uint8_t* Tb = reinterpret_cast<const uint8_t*>(Tt0);
        #pragma unroll
        for (int kki = 0; kki < 8; ++kki) {
            if (has1) {
                if (kki == 0) STAGE_GROUP(Tt1, j0t1, 0);
                if (kki == 1) STAGE_GROUP(Tt1, j0t1, 1);
                if (kki == 2) STAGE_GROUP(Tt1, j0t1, 2);
                if (kki == 3) STAGE_GROUP(Tt1, j0t1, 3);
                if (kki == 4) STAGE_ROW64(Tt1, j0t1);
            }
            bf16x8 af[4], bfr[4];
            LOADB(bfr, kki * 2 + 0);
            LOADA(af, Tb, kki, 0);
            DOMFMA(af, bfr);
            LOADB(bfr, kki * 2 + 1);
            LOADA(af, Tb, kki, 1);
            DOMFMA(af, bfr);
        }
    }
    __syncthreads();          // buf1 writes visible; also separates buf0 reuse

    // ---- stores of tile0 issue here: they drain under tile1's compute ----
    STORE_TILE(j0t0);

    if (has1) {
        #pragma unroll
        for (int i = 0; i < 4; ++i)
            #pragma unroll
            for (int jn = 0; jn < 4; ++jn)
                acc[i][jn] = (floatx4){0.f, 0.f, 0.f, 0.f};
        const uint8_t* Tb = reinterpret_cast<const uint8_t*>(Tt1);
        #pragma unroll
        for (int kki = 0; kki < 8; ++kki) {
            bf16x8 af[4], bfr[4];
            LOADB(bfr, kki * 2 + 0);
            LOADA(af, Tb, kki, 0);
            DOMFMA(af, bfr);
            LOADB(bfr, kki * 2 + 1);
            LOADA(af, Tb, kki, 1);
            DOMFMA(af, bfr);
        }
        STORE_TILE(j0t1);
    }
}

extern "C" void kernel_launch(void* const* d_in, const int* in_sizes, int n_in,
                              void* d_out, int out_size, void* d_ws, size_t ws_size,
                              hipStream_t stream) {
    const float* spec = (const float*)d_in[0];   // [16][1][256][4096] fp32
    const float* ker  = (const float*)d_in[1];   // [512][256] fp32
    float* out = (float*)d_out;                  // [16][1048832] fp32

    bf16* kbF = (bf16*)d_ws;                     // 256 KB scratch

    build_kb<<<512, 256, 0, stream>>>(ker, kbF);
    imdct_gemm<<<dim3(33, NB), 256, 0, stream>>>(spec, kbF, out);
}

// Round 5
// 142.653 us; speedup vs baseline: 1.0201x; 1.0201x over previous
//
#include <hip/hip_runtime.h>
#include <stdint.h>

#define NFREQ 256
#define NB 16
#define NT 4096
#define LOUT 1048832          // (4096+1)*256
#define TROWS 65              // t = j0-1 .. j0+63
#define TROW 132              // u32 per T row: 128 payload + 4 pad (528 B, 16B-aligned)

typedef __bf16 bf16;
typedef __bf16 bf16x8 __attribute__((ext_vector_type(8)));
typedef float floatx4 __attribute__((ext_vector_type(4)));

__device__ inline uint32_t f_as_u(float x) { union { float f; uint32_t u; } v; v.f = x; return v.u; }
__device__ inline uint32_t bf16r(float x) {     // RNE bf16 bits in low 16
    uint32_t u = f_as_u(x);
    return (u + 0x7fffu + ((u >> 16) & 1u)) >> 16;
}

// kbF frag-major: kbF[k'/32][n][k'%32] = Kb[n][k'],
//   Kb[n][f'] = (f'<256 ? K[n+256][f'] : K[n][f'-256]) / 128  (bf16 RNE)
__global__ __launch_bounds__(256) void build_kb(const float* __restrict__ ker,
                                                bf16* __restrict__ kbF) {
    int idx = blockIdx.x * 256 + threadIdx.x;   // 131072 total
    int n = idx >> 9, f = idx & 511;
    float v = (f < 256) ? ker[(n + 256) * 256 + f] : ker[n * 256 + (f - 256)];
    uint32_t rr = bf16r(v * 0.0078125f);
    union { uint16_t u; bf16 b; } o; o.u = (uint16_t)rr;
    kbF[((size_t)(f >> 5) * 256 + n) * 32 + (f & 31)] = o.b;
}

// ---- T14 staging: ISSUE (global->VGPR, all 65 in flight) / PACK (VGPR->LDS) ----
#define STAGE_ISSUE(J0) { \
    _Pragma("unroll") \
    for (int r_ = 0; r_ < 64; ++r_) { \
        int tc_ = r_ >> 5, fpi_ = r_ & 31; \
        int f_ = (fpw + fpi_) * 2 + lpar; \
        int t_ = (J0) - 1 + tc_ * 32 + lt; \
        vs_[r_] = ((unsigned)t_ < (unsigned)NT) ? sb[(size_t)f_ * NT + t_] : 0.0f; } \
    { int f_ = w * 64 + lane; int te_ = (J0) + 63; \
      vs_[64] = ((unsigned)te_ < (unsigned)NT) ? sb[(size_t)f_ * NT + te_] : 0.0f; } }

#define STAGE_PACK(TtB) { \
    _Pragma("unroll") \
    for (int r_ = 0; r_ < 64; r_ += 2) { \
        int tc_ = r_ >> 5, fpi_ = r_ & 31; \
        int tl_ = tc_ * 32 + lt; \
        uint32_t h0_ = bf16r(vs_[r_]);     uint32_t o0_ = (uint32_t)__shfl_xor((int)h0_, 1); \
        uint32_t h1_ = bf16r(vs_[r_ + 1]); uint32_t o1_ = (uint32_t)__shfl_xor((int)h1_, 1); \
        if (lpar == 0) { \
            uint2 pk_; pk_.x = (h0_ & 0xffffu) | (o0_ << 16); pk_.y = (h1_ & 0xffffu) | (o1_ << 16); \
            *reinterpret_cast<uint2*>(&(TtB)[tl_ * TROW + fpw + fpi_]) = pk_; } } \
    { uint32_t h_ = bf16r(vs_[64]); uint32_t o_ = (uint32_t)__shfl_xor((int)h_, 1); \
      if (lpar == 0) (TtB)[64 * TROW + w * 32 + lt] = (h_ & 0xffffu) | (o_ << 16); } }

#define LOADB(dst, c) { \
    _Pragma("unroll") \
    for (int jn_ = 0; jn_ < 4; ++jn_) \
        dst[jn_] = *reinterpret_cast<const bf16x8*>( \
            kbw + (size_t)(c) * 8192 + (jn_ * 16 + row16) * 32 + q * 8); }

#define LOADA(dst, Tb, c) { \
    _Pragma("unroll") \
    for (int i_ = 0; i_ < 4; ++i_) \
        dst[i_] = *reinterpret_cast<const bf16x8*>( \
            (Tb) + (size_t)(i_ * 16 + row16 + ((c) >> 3)) * 528 + ((c) & 7) * 64 + q * 16); }

#define DOMFMA(af_, bf_) { \
    _Pragma("unroll") \
    for (int i_ = 0; i_ < 4; ++i_) \
        _Pragma("unroll") \
        for (int jn_ = 0; jn_ < 4; ++jn_) \
            acc[i_][jn_] = __builtin_amdgcn_mfma_f32_16x16x32_bf16(af_[i_], bf_[jn_], acc[i_][jn_], 0, 0, 0); }

// 16 chunks, B register ping-pong (chunk c+1's global loads in flight under
// chunk c's MFMAs; counted vmcnt from reg deps, no drain)
#define COMPUTE_TILE(TtB) { \
    const uint8_t* Tb_ = reinterpret_cast<const uint8_t*>(TtB); \
    bf16x8 bP[4], bQ[4], af[4]; \
    LOADB(bP, 0); \
    _Pragma("unroll") \
    for (int cc = 0; cc < 8; ++cc) { \
        LOADB(bQ, cc * 2 + 1); \
        LOADA(af, Tb_, cc * 2); \
        DOMFMA(af, bP); \
        if (cc < 7) LOADB(bP, cc * 2 + 2); \
        LOADA(af, Tb_, cc * 2 + 1); \
        DOMFMA(af, bQ); \
    } }

#define STORE_TILE(J0) { \
    _Pragma("unroll") \
    for (int i_ = 0; i_ < 4; ++i_) { \
        _Pragma("unroll") \
        for (int e_ = 0; e_ < 4; ++e_) { \
            int j_ = (J0) + i_ * 16 + q * 4 + e_; \
            if (j_ <= 4096) { \
                float* orow_ = out + (size_t)b * LOUT + (size_t)j_ * 256 + w * 64; \
                _Pragma("unroll") \
                for (int jn_ = 0; jn_ < 4; ++jn_) \
                    orow_[jn_ * 16 + row16] = acc[i_][jn_][e_]; } } } }

// out[b][j*256+n] = sum_{f'<512} Avirt[j][f'] * Kb[n][f'],
//   Avirt[j][f'] = spec[b][f'&255][j-1+(f'>=256)]   (0 outside t-range)
// Two 64j x 256n tiles per block, double-buffered LDS, T14 schedule:
//   issue0 -> pack0 -> bar -> issue1 -> compute0 -> pack1 -> bar
//   -> store0(fire) -> compute1 -> store1
// No barrier ever waits on stores or in-flight stage loads; tile1's HBM
// latency hides under tile0's compute; tile0's stores drain under tile1's.
__global__ __launch_bounds__(256, 2) void imdct_gemm(const float* __restrict__ spec,
                                                     const bf16* __restrict__ kbF,
                                                     float* __restrict__ out) {
    __shared__ uint32_t Tt[2][TROWS * TROW];    // 2 x 34320 B = 68640 -> 2 blocks/CU

    const int b  = blockIdx.y;
    const int tid = threadIdx.x, lane = tid & 63, w = tid >> 6;
    const int j0t0 = blockIdx.x * 128;           // tile0 j-base
    const int j0t1 = j0t0 + 64;                  // tile1 j-base
    const bool has1 = (blockIdx.x < 32);         // bx=32 -> only boundary tile
    const float* sb = spec + (size_t)b * NFREQ * NT;

    const int lpar = lane & 1, lt = lane >> 1;
    const int fpw = w * 32;
    const int row16 = lane & 15, q = lane >> 4;
    const bf16* kbw = kbF + (size_t)w * 64 * 32;   // wave's n-slice base
    uint32_t* Tt0 = &Tt[0][0];
    uint32_t* Tt1 = &Tt[1][0];

    float vs_[65];
    floatx4 acc[4][4] = {};

    // tile0: issue + pack (one exposed HBM latency, all 65 loads in flight)
    STAGE_ISSUE(j0t0);
    STAGE_PACK(Tt0);
    __syncthreads();

    if (has1) { STAGE_ISSUE(j0t1); }   // fire tile1's loads; ride under compute0

    COMPUTE_TILE(Tt0);

    if (has1) {
        STAGE_PACK(Tt1);               // loads returned long ago; VALU + ds_write
        __syncthreads();               // cheap: no stores outstanding yet
        STORE_TILE(j0t0);              // fire; drains under compute1
        #pragma unroll
        for (int i = 0; i < 4; ++i)
            #pragma unroll
            for (int jn = 0; jn < 4; ++jn)
                acc[i][jn] = (floatx4){0.f, 0.f, 0.f, 0.f};
        COMPUTE_TILE(Tt1);
        STORE_TILE(j0t1);
    } else {
        STORE_TILE(j0t0);
    }
}

extern "C" void kernel_launch(void* const* d_in, const int* in_sizes, int n_in,
                              void* d_out, int out_size, void* d_ws, size_t ws_size,
                              hipStream_t stream) {
    const float* spec = (const float*)d_in[0];   // [16][1][256][4096] fp32
    const float* ker  = (const float*)d_in[1];   // [512][256] fp32
    float* out = (float*)d_out;                  // [16][1048832] fp32

    bf16* kbF = (bf16*)d_ws;                     // 256 KB scratch

    build_kb<<<512, 256, 0, stream>>>(ker, kbF);
    imdct_gemm<<<dim3(33, NB), 256, 0, stream>>>(spec, kbF, out);
}

// Round 6
// 140.226 us; speedup vs baseline: 1.0377x; 1.0173x over previous
//
#include <hip/hip_runtime.h>
#include <stdint.h>

#define NFREQ 256
#define NB 16
#define NT 4096
#define LOUT 1048832          // (4096+1)*256
#define TROWS 65              // t = j0-1 .. j0+63
#define TROW 132              // u32 per T row: 128 payload + 4 pad (528 B, 16B-aligned)

typedef __bf16 bf16;
typedef __bf16 bf16x8 __attribute__((ext_vector_type(8)));
typedef float floatx4 __attribute__((ext_vector_type(4)));

__device__ inline uint32_t f_as_u(float x) { union { float f; uint32_t u; } v; v.f = x; return v.u; }
__device__ inline uint32_t bf16r(float x) {     // RNE bf16 bits in low 16
    uint32_t u = f_as_u(x);
    return (u + 0x7fffu + ((u >> 16) & 1u)) >> 16;
}

// kbF frag-major: kbF[k'/32][n][k'%32] = Kb[n][k'],
//   Kb[n][f'] = (f'<256 ? K[n+256][f'] : K[n][f'-256]) / 128  (bf16 RNE)
__global__ __launch_bounds__(256) void build_kb(const float* __restrict__ ker,
                                                bf16* __restrict__ kbF) {
    int idx = blockIdx.x * 256 + threadIdx.x;   // 131072 total
    int n = idx >> 9, f = idx & 511;
    float v = (f < 256) ? ker[(n + 256) * 256 + f] : ker[n * 256 + (f - 256)];
    uint32_t rr = bf16r(v * 0.0078125f);
    union { uint16_t u; bf16 b; } o; o.u = (uint16_t)rr;
    kbF[((size_t)(f >> 5) * 256 + n) * 32 + (f & 31)] = o.b;
}

// out[b][j*256+n] = sum_{f'<512} Avirt[j][f'] * Kb[n][f'],
//   Avirt[j][f'] = spec[b][f'&255][j-1+(f'>=256)]   (0 outside t-range)
// Geometry identical to the best-measured variant (64j x 256n, 4 blocks/CU).
// ONLY change vs that variant: stage and compute are ROLLED runtime loops
// (#pragma unroll 1) so the hot code is ~3 KB and stays I$-resident.
// Theory: all previous ~60us variants were ~25-30 KB straight-line bodies
// that thrashed the 32 KB I-cache; every execution pipe idled on front-end
// instruction fetch from L2 (all PMC pipes <25% with 3x headroom vs roofline).
__global__ __launch_bounds__(256, 4) void imdct_gemm(const float* __restrict__ spec,
                                                     const bf16* __restrict__ kbF,
                                                     float* __restrict__ out) {
    __shared__ uint32_t Tt[TROWS * TROW];    // 34320 B -> 4 blocks/CU

    const int jt = blockIdx.x;               // 0..64
    const int b  = blockIdx.y;
    const int tid = threadIdx.x, lane = tid & 63, w = tid >> 6;
    const int j0 = jt * 64;
    const float* sb = spec + (size_t)b * NFREQ * NT;

    // ---- stage T: T[t_local][f] bf16, t = j0-1+t_local, rows 0..64 ----
    {
        const int lpar = lane & 1, lt = lane >> 1;
        const int fpw = w * 32;              // wave's f-pair base
        #pragma unroll 1
        for (int rb = 0; rb < 4; ++rb) {     // ROLLED: 4 iterations share code
            const int tc = rb >> 1;          // t chunk (0 or 1)
            const int fh = (rb & 1) * 16;    // f-pair half within wave's 32
            const int t  = j0 - 1 + tc * 32 + lt;
            const bool tok = ((unsigned)t < (unsigned)NT);
            const float* pb = sb + (size_t)((fpw + fh) * 2 + lpar) * NT + t;
            float v[16];
            #pragma unroll
            for (int i = 0; i < 16; ++i)     // independent loads, 128B segments
                v[i] = tok ? pb[(size_t)i * 2 * NT] : 0.0f;
            const int tl = tc * 32 + lt;
            uint32_t* dst = &Tt[tl * TROW + fpw + fh];
            #pragma unroll
            for (int i = 0; i < 16; i += 4) {
                uint32_t pk[4];
                #pragma unroll
                for (int u = 0; u < 4; ++u) {
                    uint32_t h = bf16r(v[i + u]);
                    uint32_t o = (uint32_t)__shfl_xor((int)h, 1);
                    pk[u] = (h & 0xffffu) | (o << 16);
                }
                if (lpar == 0) {
                    uint4 q4; q4.x = pk[0]; q4.y = pk[1]; q4.z = pk[2]; q4.w = pk[3];
                    *reinterpret_cast<uint4*>(dst + i) = q4;
                }
            }
        }
        // row 64 (t = j0+63)
        {
            int f = w * 64 + lane;
            int te = j0 + 63;
            float v = ((unsigned)te < (unsigned)NT) ? sb[(size_t)f * NT + te] : 0.0f;
            uint32_t h = bf16r(v); uint32_t o = (uint32_t)__shfl_xor((int)h, 1);
            if (lpar == 0) Tt[64 * TROW + w * 32 + lt] = (h & 0xffffu) | (o << 16);
        }
    }
    __syncthreads();                         // the ONLY barrier

    const int row16 = lane & 15, q = lane >> 4;
    floatx4 acc[4][4] = {};
    const uint8_t* Tb = reinterpret_cast<const uint8_t*>(Tt);
    const bf16* kbw = kbF + (size_t)w * 64 * 32 + (row16 * 32 + q * 8);  // lane's B base

    #pragma unroll 1
    for (int kki = 0; kki < 8; ++kki) {      // ROLLED: 8 iterations share code
        const int toff = kki >> 2;           // +1 t row for k' >= 256
        const int kbyte = (kki & 3) * 128;   // byte col within a T row
        const uint8_t* ta = Tb + (size_t)(row16 + toff) * 528 + kbyte + q * 16;
        const bf16* kb2 = kbw + (size_t)kki * 16384;
        #pragma unroll
        for (int ks = 0; ks < 2; ++ks) {
            bf16x8 af[4], bfr[4];
            #pragma unroll
            for (int jn = 0; jn < 4; ++jn)   // imm offsets 0,1024,2048,3072
                bfr[jn] = *reinterpret_cast<const bf16x8*>(
                    kb2 + (size_t)ks * 8192 + jn * 512);
            #pragma unroll
            for (int i = 0; i < 4; ++i)      // ds imm offsets 0,8448,16896,25344
                af[i] = *reinterpret_cast<const bf16x8*>(ta + ks * 64 + i * 8448);
            #pragma unroll
            for (int i = 0; i < 4; ++i)
                #pragma unroll
                for (int jn = 0; jn < 4; ++jn)
                    acc[i][jn] = __builtin_amdgcn_mfma_f32_16x16x32_bf16(af[i], bfr[jn], acc[i][jn], 0, 0, 0);
        }
    }

    // epilogue: C/D layout col=lane&15 (n), row=q*4+e (j within 16)
    // (unrolled: acc indices must stay compile-time; ~1 KB of code)
    #pragma unroll
    for (int i = 0; i < 4; ++i) {
        #pragma unroll
        for (int e = 0; e < 4; ++e) {
            int j = j0 + i * 16 + q * 4 + e;
            if (j <= 4096) {
                float* orow = out + (size_t)b * LOUT + (size_t)j * 256 + w * 64;
                #pragma unroll
                for (int jn = 0; jn < 4; ++jn)
                    orow[jn * 16 + row16] = acc[i][jn][e];
            }
        }
    }
}

extern "C" void kernel_launch(void* const* d_in, const int* in_sizes, int n_in,
                              void* d_out, int out_size, void* d_ws, size_t ws_size,
                              hipStream_t stream) {
    const float* spec = (const float*)d_in[0];   // [16][1][256][4096] fp32
    const float* ker  = (const float*)d_in[1];   // [512][256] fp32
    float* out = (float*)d_out;                  // [16][1048832] fp32

    bf16* kbF = (bf16*)d_ws;                     // 256 KB scratch

    build_kb<<<512, 256, 0, stream>>>(ker, kbF);
    imdct_gemm<<<dim3(65, NB), 256, 0, stream>>>(spec, kbF, out);
}